// Round 7
// baseline (205.007 us; speedup 1.0000x reference)
//
#include <hip/hip_runtime.h>
#include <hip/hip_bf16.h>

typedef __attribute__((ext_vector_type(8))) short short8;
typedef __attribute__((ext_vector_type(4))) short short4v;
typedef __attribute__((ext_vector_type(4))) float f32x4;

#define S_LEN 2048
#define DM 1024
#define NH 16
#define HD 64

__device__ __forceinline__ short f2b(float f) {
    __hip_bfloat16 h = __float2bfloat16(f);
    return *reinterpret_cast<short*>(&h);
}

// ---------------- convert x (fp32 -> bf16) ----------------
__global__ void k_convert_x(const float* __restrict__ x, short* __restrict__ xb) {
    size_t i = ((size_t)blockIdx.x * blockDim.x + threadIdx.x) * 4;
    f32x4 v = *reinterpret_cast<const f32x4*>(x + i);
    short4v o;
    for (int e = 0; e < 4; e++) o[e] = f2b(v[e]);
    *reinterpret_cast<short4v*>(xb + i) = o;
}

// ---------------- transpose + convert all four W (fp32 [K][N] -> bf16 [N][K]) ----------------
__global__ void k_transpose_w4(const float* __restrict__ W0, const float* __restrict__ W1,
                               const float* __restrict__ W2, const float* __restrict__ W3,
                               short* __restrict__ T0, short* __restrict__ T1,
                               short* __restrict__ T2, short* __restrict__ T3) {
    __shared__ float tile[32][33];
    const int z = blockIdx.z;
    const float* W = (z == 0) ? W0 : (z == 1) ? W1 : (z == 2) ? W2 : W3;
    short* Wt = (z == 0) ? T0 : (z == 1) ? T1 : (z == 2) ? T2 : T3;
    int tx = threadIdx.x, ty = threadIdx.y;
    int nb = blockIdx.x * 32, kb = blockIdx.y * 32;
    for (int i = 0; i < 4; i++)
        tile[ty + i * 8][tx] = W[(size_t)(kb + ty + i * 8) * DM + nb + tx];
    __syncthreads();
    for (int i = 0; i < 4; i++)
        Wt[(size_t)(nb + ty + i * 8) * DM + kb + tx] = f2b(tile[tx][ty + i * 8]);
}

// ---------------- fused QKV GEMM: C = xb @ W + bias  (R3-proven reg staging) ----------------
// Q scaled by (1/sqrt(1024))*log2(e). z==2 writes presentV (f32) + TRANSPOSED bf16 V^T [bh][d][s].
__global__ __launch_bounds__(256) void k_gemm_qkv(
    const short* __restrict__ xb,
    const short* __restrict__ Wqt, const short* __restrict__ Wkt, const short* __restrict__ Wvt,
    const float* __restrict__ bq, const float* __restrict__ bk, const float* __restrict__ bv,
    short* __restrict__ Qb, short* __restrict__ Kb, short* __restrict__ Vtg,
    float* __restrict__ pK, float* __restrict__ pV)
{
    __shared__ alignas(16) short As[128][72];
    __shared__ alignas(16) short Bs[128][72];
    const int z = blockIdx.z;
    const short* Wt  = (z == 0) ? Wqt : (z == 1) ? Wkt : Wvt;
    const float* bias = (z == 0) ? bq : (z == 1) ? bk : bv;
    const int t = threadIdx.x;
    const int brow = blockIdx.y * 128, bcol = blockIdx.x * 128;
    const int w = t >> 6, l = t & 63;
    const int wr = w >> 1, wc = w & 1;
    const int lr = l & 15, lg = l >> 4;
    f32x4 acc[4][4];
    for (int m = 0; m < 4; m++) for (int n = 0; n < 4; n++) acc[m][n] = (f32x4)0.0f;

    for (int k0 = 0; k0 < DM; k0 += 64) {
        __syncthreads();
        for (int i = 0; i < 4; i++) {
            int idx = i * 256 + t;
            int r = idx >> 3, c8 = (idx & 7) * 8;
            *reinterpret_cast<short8*>(&As[r][c8]) =
                *reinterpret_cast<const short8*>(&xb[(size_t)(brow + r) * DM + k0 + c8]);
            *reinterpret_cast<short8*>(&Bs[r][c8]) =
                *reinterpret_cast<const short8*>(&Wt[(size_t)(bcol + r) * DM + k0 + c8]);
        }
        __syncthreads();
        for (int ks = 0; ks < 2; ks++) {
            short8 a[4], bb[4];
            const int kk = ks * 32 + lg * 8;
            for (int m = 0; m < 4; m++)
                a[m] = *reinterpret_cast<const short8*>(&As[wr * 64 + m * 16 + lr][kk]);
            for (int n = 0; n < 4; n++)
                bb[n] = *reinterpret_cast<const short8*>(&Bs[wc * 64 + n * 16 + lr][kk]);
            for (int m = 0; m < 4; m++)
                for (int n = 0; n < 4; n++)
                    acc[m][n] = __builtin_amdgcn_mfma_f32_16x16x32_bf16(a[m], bb[n], acc[m][n], 0, 0, 0);
        }
    }
    for (int m = 0; m < 4; m++)
        for (int n = 0; n < 4; n++) {
            int row = brow + wr * 64 + m * 16 + lg * 4;
            int col = bcol + wc * 64 + n * 16 + lr;
            float bv_ = bias[col];
            int b_ = row >> 11, sI0 = row & 2047, hI = col >> 6, dh = col & 63;
            if (z == 0) {
                for (int r = 0; r < 4; r++) {
                    float v = acc[m][n][r] + bv_;
                    Qb[(size_t)(row + r) * DM + col] = f2b(v * 0.0450842200575152f);  // 1/32*log2(e)
                }
            } else if (z == 1) {
                for (int r = 0; r < 4; r++) {
                    int rr = row + r;
                    float v = acc[m][n][r] + bv_;
                    Kb[(size_t)rr * DM + col] = f2b(v);
                    pK[(((size_t)(b_ * NH + hI)) * S_LEN + (sI0 + r)) * HD + dh] = v;
                }
            } else {
                short4v tv;
                for (int r = 0; r < 4; r++) {
                    float v = acc[m][n][r] + bv_;
                    pV[(((size_t)(b_ * NH + hI)) * S_LEN + (sI0 + r)) * HD + dh] = v;
                    tv[r] = f2b(v);
                }
                *reinterpret_cast<short4v*>(
                    &Vtg[((size_t)((b_ * NH + hI) * HD + dh)) * S_LEN + sI0]) = tv;
            }
        }
}

// ---------------- final GEMM: out = attn @ Wo + bo  (R3-proven) ----------------
__global__ __launch_bounds__(256) void k_gemm_o(
    const short* __restrict__ Ab, const short* __restrict__ Wot,
    const float* __restrict__ bo, float* __restrict__ out)
{
    __shared__ alignas(16) short As[128][72];
    __shared__ alignas(16) short Bs[128][72];
    const int t = threadIdx.x;
    const int brow = blockIdx.y * 128, bcol = blockIdx.x * 128;
    const int w = t >> 6, l = t & 63;
    const int wr = w >> 1, wc = w & 1;
    const int lr = l & 15, lg = l >> 4;
    f32x4 acc[4][4];
    for (int m = 0; m < 4; m++) for (int n = 0; n < 4; n++) acc[m][n] = (f32x4)0.0f;

    for (int k0 = 0; k0 < DM; k0 += 64) {
        __syncthreads();
        for (int i = 0; i < 4; i++) {
            int idx = i * 256 + t;
            int r = idx >> 3, c8 = (idx & 7) * 8;
            *reinterpret_cast<short8*>(&As[r][c8]) =
                *reinterpret_cast<const short8*>(&Ab[(size_t)(brow + r) * DM + k0 + c8]);
            *reinterpret_cast<short8*>(&Bs[r][c8]) =
                *reinterpret_cast<const short8*>(&Wot[(size_t)(bcol + r) * DM + k0 + c8]);
        }
        __syncthreads();
        for (int ks = 0; ks < 2; ks++) {
            short8 a[4], bb[4];
            const int kk = ks * 32 + lg * 8;
            for (int m = 0; m < 4; m++)
                a[m] = *reinterpret_cast<const short8*>(&As[wr * 64 + m * 16 + lr][kk]);
            for (int n = 0; n < 4; n++)
                bb[n] = *reinterpret_cast<const short8*>(&Bs[wc * 64 + n * 16 + lr][kk]);
            for (int m = 0; m < 4; m++)
                for (int n = 0; n < 4; n++)
                    acc[m][n] = __builtin_amdgcn_mfma_f32_16x16x32_bf16(a[m], bb[n], acc[m][n], 0, 0, 0);
        }
    }
    for (int m = 0; m < 4; m++)
        for (int n = 0; n < 4; n++) {
            int row = brow + wr * 64 + m * 16 + lg * 4;
            int col = bcol + wc * 64 + n * 16 + lr;
            float bv_ = bo[col];
            for (int r = 0; r < 4; r++)
                out[(size_t)(row + r) * DM + col] = acc[m][n][r] + bv_;
        }
}

// ---------------- causal flash attention: NO LDS, NO barriers ----------------
// grid 512, pair tiling (bx, 31-bx) = uniform 33 tiles/wave; waves fully independent.
// Swapped QK^T (R6-proven); PV A-fragments read straight from global V^T (L2-resident).
__global__ __launch_bounds__(256) void k_attn(
    const short* __restrict__ Qb, const short* __restrict__ Kb,
    const short* __restrict__ Vtg, short* __restrict__ Ab)
{
    const int bid = blockIdx.x;
    const int orig = (bid & 7) * 64 + (bid >> 3);    // XCD-chunked: 4 (b,h) pairs per XCD
    const int bx = orig & 15, h = (orig >> 4) & 15, b = orig >> 8;
    const int t = threadIdx.x, w = t >> 6, l = t & 63;
    const int lr = l & 15, lg = l >> 4;
    const size_t base = (size_t)b * S_LEN * DM + (size_t)h * HD;
    const short* Qp = Qb + base;
    const short* Kp = Kb + base;
    const short* Vp = Vtg + (size_t)(b * NH + h) * HD * S_LEN;   // [d][s]
    // K permutation (R6-proven): physical slot cg*16+lr holds logical key (cg>>1)*32+(cg&1)*4+lperm
    const int lperm = (lr >> 2) * 8 + (lr & 3);

    for (int phase = 0; phase < 2; ++phase) {
        const int qt = phase ? 31 - bx : bx;
        const int qbase = qt * 64 + w * 16;
        const int qrow = qbase + lr;
        short8 qf0 = *reinterpret_cast<const short8*>(Qp + (size_t)qrow * DM + lg * 8);
        short8 qf1 = *reinterpret_cast<const short8*>(Qp + (size_t)qrow * DM + 32 + lg * 8);
        f32x4 o[4];
#pragma unroll
        for (int dg = 0; dg < 4; dg++) o[dg] = (f32x4)0.0f;
        float mrun = -INFINITY, lrun = 0.0f;

        // per-lane row pointers; K rows advance +64*DM, V^T rows advance +64 per tile
        const short* kr0 = Kp + (size_t)(lperm +  0) * DM + lg * 8;
        const short* kr1 = Kp + (size_t)(lperm +  4) * DM + lg * 8;
        const short* kr2 = Kp + (size_t)(lperm + 32) * DM + lg * 8;
        const short* kr3 = Kp + (size_t)(lperm + 36) * DM + lg * 8;
        const short* vr0 = Vp + (size_t)(lr +  0) * S_LEN + lg * 8;
        const short* vr1 = Vp + (size_t)(lr + 16) * S_LEN + lg * 8;
        const short* vr2 = Vp + (size_t)(lr + 32) * S_LEN + lg * 8;
        const short* vr3 = Vp + (size_t)(lr + 48) * S_LEN + lg * 8;

        short8 kc[2][4], vc[2][4];
#pragma unroll
        for (int ks = 0; ks < 2; ks++) {
            kc[ks][0] = *reinterpret_cast<const short8*>(kr0 + ks * 32);
            kc[ks][1] = *reinterpret_cast<const short8*>(kr1 + ks * 32);
            kc[ks][2] = *reinterpret_cast<const short8*>(kr2 + ks * 32);
            kc[ks][3] = *reinterpret_cast<const short8*>(kr3 + ks * 32);
            vc[ks][0] = *reinterpret_cast<const short8*>(vr0 + ks * 32);
            vc[ks][1] = *reinterpret_cast<const short8*>(vr1 + ks * 32);
            vc[ks][2] = *reinterpret_cast<const short8*>(vr2 + ks * 32);
            vc[ks][3] = *reinterpret_cast<const short8*>(vr3 + ks * 32);
        }

        for (int j = 0; j <= qt; ++j) {
            const int kbase = j * 64;
            // ---- swapped QK^T: S^T[key][q] ----
            f32x4 s[4];
#pragma unroll
            for (int cg = 0; cg < 4; cg++) s[cg] = (f32x4)0.0f;
#pragma unroll
            for (int ks = 0; ks < 2; ks++) {
                const short8 qf = ks ? qf1 : qf0;
#pragma unroll
                for (int cg = 0; cg < 4; cg++)
                    s[cg] = __builtin_amdgcn_mfma_f32_16x16x32_bf16(kc[ks][cg], qf, s[cg], 0, 0, 0);
            }
            if (j < qt) {   // prefetch next K tile; overlaps softmax+PV
                kr0 += 64 * DM; kr1 += 64 * DM; kr2 += 64 * DM; kr3 += 64 * DM;
#pragma unroll
                for (int ks = 0; ks < 2; ks++) {
                    kc[ks][0] = *reinterpret_cast<const short8*>(kr0 + ks * 32);
                    kc[ks][1] = *reinterpret_cast<const short8*>(kr1 + ks * 32);
                    kc[ks][2] = *reinterpret_cast<const short8*>(kr2 + ks * 32);
                    kc[ks][3] = *reinterpret_cast<const short8*>(kr3 + ks * 32);
                }
            }
            if (j == qt) {  // causal mask: s[cg][r] is logical key (cg>>1)*32+lg*8+(cg&1)*4+r
#pragma unroll
                for (int cg = 0; cg < 4; cg++)
#pragma unroll
                    for (int r = 0; r < 4; r++) {
                        int n = ((cg >> 1) << 5) + (lg << 3) + ((cg & 1) << 2) + r;
                        if (kbase + n > qrow) s[cg][r] = -INFINITY;
                    }
            }
            // ---- in-register online softmax (exp2 domain) ----
            float mx0 = fmaxf(fmaxf(s[0][0], s[0][1]), fmaxf(s[0][2], s[0][3]));
            float mx1 = fmaxf(fmaxf(s[1][0], s[1][1]), fmaxf(s[1][2], s[1][3]));
            float mx2 = fmaxf(fmaxf(s[2][0], s[2][1]), fmaxf(s[2][2], s[2][3]));
            float mx3 = fmaxf(fmaxf(s[3][0], s[3][1]), fmaxf(s[3][2], s[3][3]));
            float vmax = fmaxf(fmaxf(mx0, mx1), fmaxf(mx2, mx3));
            vmax = fmaxf(vmax, __shfl_xor(vmax, 16));
            vmax = fmaxf(vmax, __shfl_xor(vmax, 32));
            if (!__all(vmax - mrun <= 8.0f)) {   // defer-max (T13)
                float mn = fmaxf(mrun, vmax);
                float scl = exp2f(mrun - mn);
                mrun = mn; lrun *= scl;
#pragma unroll
                for (int dg = 0; dg < 4; dg++)
#pragma unroll
                    for (int r = 0; r < 4; r++) o[dg][r] *= scl;
            }
            float rs = 0.0f;
#pragma unroll
            for (int cg = 0; cg < 4; cg++)
#pragma unroll
                for (int r = 0; r < 4; r++) {
                    float p = exp2f(s[cg][r] - mrun);
                    s[cg][r] = p;
                    rs += p;
                }
            rs += __shfl_xor(rs, 16);
            rs += __shfl_xor(rs, 32);
            lrun += rs;
            // ---- P already in B-fragment order: in-lane pack ----
            short8 pf0, pf1;
#pragma unroll
            for (int r = 0; r < 4; r++) {
                pf0[r] = f2b(s[0][r]); pf0[4 + r] = f2b(s[1][r]);
                pf1[r] = f2b(s[2][r]); pf1[4 + r] = f2b(s[3][r]);
            }
            // ---- PV: O^T[d][q] = mfma(V^T_frag, P_frag) ----
#pragma unroll
            for (int ks = 0; ks < 2; ks++) {
                const short8 pf = ks ? pf1 : pf0;
#pragma unroll
                for (int dg = 0; dg < 4; dg++)
                    o[dg] = __builtin_amdgcn_mfma_f32_16x16x32_bf16(vc[ks][dg], pf, o[dg], 0, 0, 0);
            }
            if (j < qt) {   // prefetch next V^T tile; overlaps next QK^T+softmax
                vr0 += 64; vr1 += 64; vr2 += 64; vr3 += 64;
#pragma unroll
                for (int ks = 0; ks < 2; ks++) {
                    vc[ks][0] = *reinterpret_cast<const short8*>(vr0 + ks * 32);
                    vc[ks][1] = *reinterpret_cast<const short8*>(vr1 + ks * 32);
                    vc[ks][2] = *reinterpret_cast<const short8*>(vr2 + ks * 32);
                    vc[ks][3] = *reinterpret_cast<const short8*>(vr3 + ks * 32);
                }
            }
        }
        // ---- write O^T: lane holds d = dg*16+lg*4+r for its q-row ----
        short* Ap = Ab + base;
        float rinv = 1.0f / lrun;
#pragma unroll
        for (int dg = 0; dg < 4; dg++) {
            short4v ov;
#pragma unroll
            for (int r = 0; r < 4; r++) ov[r] = f2b(o[dg][r] * rinv);
            *reinterpret_cast<short4v*>(Ap + (size_t)qrow * DM + dg * 16 + lg * 4) = ov;
        }
    }
}

extern "C" void kernel_launch(void* const* d_in, const int* in_sizes, int n_in,
                              void* d_out, int out_size, void* d_ws, size_t ws_size,
                              hipStream_t stream) {
    const float* x  = (const float*)d_in[0];
    const float* Wq = (const float*)d_in[1];
    const float* bq = (const float*)d_in[2];
    const float* Wk = (const float*)d_in[3];
    const float* bk = (const float*)d_in[4];
    const float* Wv = (const float*)d_in[5];
    const float* bv = (const float*)d_in[6];
    const float* Wo = (const float*)d_in[7];
    const float* bo = (const float*)d_in[8];

    float* out = (float*)d_out;
    float* presentK = out + (size_t)4194304;
    float* presentV = presentK + (size_t)4194304;

    char* ws = (char*)d_ws;
    short* xb  = (short*)(ws);
    short* Wqt = (short*)(ws + ((size_t)8  << 20));
    short* Wkt = (short*)(ws + ((size_t)10 << 20));
    short* Wvt = (short*)(ws + ((size_t)12 << 20));
    short* Wot = (short*)(ws + ((size_t)14 << 20));
    short* Qb  = (short*)(ws + ((size_t)16 << 20));
    short* Kb  = (short*)(ws + ((size_t)24 << 20));
    short* Vtg = (short*)(ws + ((size_t)32 << 20));   // V^T bf16 [b*h][d][s]
    short* Ab  = (short*)(ws + ((size_t)40 << 20));

    k_convert_x<<<dim3(4096), dim3(256), 0, stream>>>(x, xb);
    k_transpose_w4<<<dim3(32, 32, 4), dim3(32, 8), 0, stream>>>(
        Wq, Wk, Wv, Wo, Wqt, Wkt, Wvt, Wot);
    k_gemm_qkv<<<dim3(8, 32, 3), dim3(256), 0, stream>>>(
        xb, Wqt, Wkt, Wvt, bq, bk, bv, Qb, Kb, Vtg, presentK, presentV);
    k_attn<<<dim3(512), dim3(256), 0, stream>>>(Qb, Kb, Vtg, Ab);
    k_gemm_o<<<dim3(8, 32), dim3(256), 0, stream>>>(Ab, Wot, bo, out);
}

// Round 8
// 140.873 us; speedup vs baseline: 1.4553x; 1.4553x over previous
//
#include <hip/hip_runtime.h>
#include <hip/hip_bf16.h>

typedef __attribute__((ext_vector_type(8))) short short8;
typedef __attribute__((ext_vector_type(4))) short short4v;
typedef __attribute__((ext_vector_type(4))) float f32x4;

#define S_LEN 2048
#define DM 1024
#define NH 16
#define HD 64

__device__ __forceinline__ short f2b(float f) {
    __hip_bfloat16 h = __float2bfloat16(f);
    return *reinterpret_cast<short*>(&h);
}

// ---------------- convert x (fp32 -> bf16) ----------------
__global__ void k_convert_x(const float* __restrict__ x, short* __restrict__ xb) {
    size_t i = ((size_t)blockIdx.x * blockDim.x + threadIdx.x) * 4;
    f32x4 v = *reinterpret_cast<const f32x4*>(x + i);
    short4v o;
    for (int e = 0; e < 4; e++) o[e] = f2b(v[e]);
    *reinterpret_cast<short4v*>(xb + i) = o;
}

// ---------------- transpose + convert all four W (fp32 [K][N] -> bf16 [N][K]) ----------------
__global__ void k_transpose_w4(const float* __restrict__ W0, const float* __restrict__ W1,
                               const float* __restrict__ W2, const float* __restrict__ W3,
                               short* __restrict__ T0, short* __restrict__ T1,
                               short* __restrict__ T2, short* __restrict__ T3) {
    __shared__ float tile[32][33];
    const int z = blockIdx.z;
    const float* W = (z == 0) ? W0 : (z == 1) ? W1 : (z == 2) ? W2 : W3;
    short* Wt = (z == 0) ? T0 : (z == 1) ? T1 : (z == 2) ? T2 : T3;
    int tx = threadIdx.x, ty = threadIdx.y;
    int nb = blockIdx.x * 32, kb = blockIdx.y * 32;
    for (int i = 0; i < 4; i++)
        tile[ty + i * 8][tx] = W[(size_t)(kb + ty + i * 8) * DM + nb + tx];
    __syncthreads();
    for (int i = 0; i < 4; i++)
        Wt[(size_t)(nb + ty + i * 8) * DM + kb + tx] = f2b(tile[tx][ty + i * 8]);
}

// ---------------- fused QKV GEMM (R3-proven core) ----------------
// z==0: Q bf16, scaled (1/sqrt(1024))*log2(e).
// z==1: presentK f32 + K in lane-ordered fragment layout Kfrag[bh][j][ks][cg][lane][8].
// z==2: presentV f32 + V^T in lane-ordered fragment layout Vfrag[bh][j][ks][dg][lane][8].
// Fragment layouts are the exact inverse of k_attn's (R7-proven) per-lane register maps.
__global__ __launch_bounds__(256) void k_gemm_qkv(
    const short* __restrict__ xb,
    const short* __restrict__ Wqt, const short* __restrict__ Wkt, const short* __restrict__ Wvt,
    const float* __restrict__ bq, const float* __restrict__ bk, const float* __restrict__ bv,
    short* __restrict__ Qb, short* __restrict__ Kfrag, short* __restrict__ Vfrag,
    float* __restrict__ pK, float* __restrict__ pV)
{
    __shared__ alignas(16) short As[128][72];
    __shared__ alignas(16) short Bs[128][72];
    const int z = blockIdx.z;
    const short* Wt  = (z == 0) ? Wqt : (z == 1) ? Wkt : Wvt;
    const float* bias = (z == 0) ? bq : (z == 1) ? bk : bv;
    const int t = threadIdx.x;
    const int brow = blockIdx.y * 128, bcol = blockIdx.x * 128;
    const int w = t >> 6, l = t & 63;
    const int wr = w >> 1, wc = w & 1;
    const int lr = l & 15, lg = l >> 4;
    f32x4 acc[4][4];
    for (int m = 0; m < 4; m++) for (int n = 0; n < 4; n++) acc[m][n] = (f32x4)0.0f;

    for (int k0 = 0; k0 < DM; k0 += 64) {
        __syncthreads();
        for (int i = 0; i < 4; i++) {
            int idx = i * 256 + t;
            int r = idx >> 3, c8 = (idx & 7) * 8;
            *reinterpret_cast<short8*>(&As[r][c8]) =
                *reinterpret_cast<const short8*>(&xb[(size_t)(brow + r) * DM + k0 + c8]);
            *reinterpret_cast<short8*>(&Bs[r][c8]) =
                *reinterpret_cast<const short8*>(&Wt[(size_t)(bcol + r) * DM + k0 + c8]);
        }
        __syncthreads();
        for (int ks = 0; ks < 2; ks++) {
            short8 a[4], bb[4];
            const int kk = ks * 32 + lg * 8;
            for (int m = 0; m < 4; m++)
                a[m] = *reinterpret_cast<const short8*>(&As[wr * 64 + m * 16 + lr][kk]);
            for (int n = 0; n < 4; n++)
                bb[n] = *reinterpret_cast<const short8*>(&Bs[wc * 64 + n * 16 + lr][kk]);
            for (int m = 0; m < 4; m++)
                for (int n = 0; n < 4; n++)
                    acc[m][n] = __builtin_amdgcn_mfma_f32_16x16x32_bf16(a[m], bb[n], acc[m][n], 0, 0, 0);
        }
    }
    for (int m = 0; m < 4; m++)
        for (int n = 0; n < 4; n++) {
            int row = brow + wr * 64 + m * 16 + lg * 4;
            int col = bcol + wc * 64 + n * 16 + lr;
            float bv_ = bias[col];
            int b_ = row >> 11, sI0 = row & 2047, hI = col >> 6, dh = col & 63;
            if (z == 0) {
                for (int r = 0; r < 4; r++) {
                    float v = acc[m][n][r] + bv_;
                    Qb[(size_t)(row + r) * DM + col] = f2b(v * 0.0450842200575152f);  // 1/32*log2(e)
                }
            } else if (z == 1) {
                for (int r = 0; r < 4; r++) {
                    float v = acc[m][n][r] + bv_;
                    int sI = sI0 + r;
                    pK[(((size_t)(b_ * NH + hI)) * S_LEN + sI) * HD + dh] = v;
                    int j = sI >> 6, kk = sI & 63;
                    int cg = ((kk >> 4) & 2) | ((kk >> 2) & 1);
                    int lrA = ((kk >> 3) & 3) * 4 + (kk & 3);
                    int lane = lrA + ((dh >> 3) & 3) * 16;
                    int ks = dh >> 5, e = dh & 7;
                    Kfrag[((((size_t)(b_ * NH + hI) * 32 + j) * 2 + ks) * 4 + cg) * 512
                          + lane * 8 + e] = f2b(v);
                }
            } else {
                int j = sI0 >> 6, ks = (sI0 >> 5) & 1;
                int dg = dh >> 4;
                int lane = (dh & 15) + ((sI0 >> 3) & 3) * 16;
                int e0 = sI0 & 7;
                short4v tv;
                for (int r = 0; r < 4; r++) {
                    float v = acc[m][n][r] + bv_;
                    pV[(((size_t)(b_ * NH + hI)) * S_LEN + (sI0 + r)) * HD + dh] = v;
                    tv[r] = f2b(v);
                }
                *reinterpret_cast<short4v*>(
                    &Vfrag[((((size_t)(b_ * NH + hI) * 32 + j) * 2 + ks) * 4 + dg) * 512
                           + lane * 8 + e0]) = tv;
            }
        }
}

// ---------------- final GEMM: out = attn @ Wo + bo  (R3-proven) ----------------
__global__ __launch_bounds__(256) void k_gemm_o(
    const short* __restrict__ Ab, const short* __restrict__ Wot,
    const float* __restrict__ bo, float* __restrict__ out)
{
    __shared__ alignas(16) short As[128][72];
    __shared__ alignas(16) short Bs[128][72];
    const int t = threadIdx.x;
    const int brow = blockIdx.y * 128, bcol = blockIdx.x * 128;
    const int w = t >> 6, l = t & 63;
    const int wr = w >> 1, wc = w & 1;
    const int lr = l & 15, lg = l >> 4;
    f32x4 acc[4][4];
    for (int m = 0; m < 4; m++) for (int n = 0; n < 4; n++) acc[m][n] = (f32x4)0.0f;

    for (int k0 = 0; k0 < DM; k0 += 64) {
        __syncthreads();
        for (int i = 0; i < 4; i++) {
            int idx = i * 256 + t;
            int r = idx >> 3, c8 = (idx & 7) * 8;
            *reinterpret_cast<short8*>(&As[r][c8]) =
                *reinterpret_cast<const short8*>(&Ab[(size_t)(brow + r) * DM + k0 + c8]);
            *reinterpret_cast<short8*>(&Bs[r][c8]) =
                *reinterpret_cast<const short8*>(&Wot[(size_t)(bcol + r) * DM + k0 + c8]);
        }
        __syncthreads();
        for (int ks = 0; ks < 2; ks++) {
            short8 a[4], bb[4];
            const int kk = ks * 32 + lg * 8;
            for (int m = 0; m < 4; m++)
                a[m] = *reinterpret_cast<const short8*>(&As[wr * 64 + m * 16 + lr][kk]);
            for (int n = 0; n < 4; n++)
                bb[n] = *reinterpret_cast<const short8*>(&Bs[wc * 64 + n * 16 + lr][kk]);
            for (int m = 0; m < 4; m++)
                for (int n = 0; n < 4; n++)
                    acc[m][n] = __builtin_amdgcn_mfma_f32_16x16x32_bf16(a[m], bb[n], acc[m][n], 0, 0, 0);
        }
    }
    for (int m = 0; m < 4; m++)
        for (int n = 0; n < 4; n++) {
            int row = brow + wr * 64 + m * 16 + lg * 4;
            int col = bcol + wc * 64 + n * 16 + lr;
            float bv_ = bo[col];
            for (int r = 0; r < 4; r++)
                out[(size_t)(row + r) * DM + col] = acc[m][n][r] + bv_;
        }
}

// ---------------- causal flash attention: 1-wave blocks, no LDS, no barriers ----------------
// grid 2048 x 64thr. Wave owns 16-row strip pair (rp, 127-rp) = uniform 33 tile-units.
// K/V fragment loads are contiguous 1KB coalesced reads from Kfrag/Vfrag (lane-ordered).
// Attention math identical to R6/R7-proven swapped-operand in-register softmax.
__global__ __launch_bounds__(64) void k_attn(
    const short* __restrict__ Qb, const short* __restrict__ Kfrag,
    const short* __restrict__ Vfrag, short* __restrict__ Ab)
{
    const int bid = blockIdx.x;
    const int orig = (bid & 7) * 256 + (bid >> 3);   // XCD-chunked: 4 (b,h) per XCD
    const int bh = orig >> 6, rp = orig & 63;
    const int h = bh & 15, b = bh >> 4;
    const int l = threadIdx.x;
    const int lr = l & 15, lg = l >> 4;
    const size_t base = (size_t)b * S_LEN * DM + (size_t)h * HD;
    const short* Qp = Qb + base;
    const short* Kbh = Kfrag + (size_t)bh * 32 * 4096;
    const short* Vbh = Vfrag + (size_t)bh * 32 * 4096;
    short* Ap = Ab + base;

    for (int phase = 0; phase < 2; ++phase) {
        const int strip = phase ? 127 - rp : rp;     // 16-row q-strip index
        const int jmax = strip >> 2;
        const int qrow = strip * 16 + lr;
        short8 qf0 = *reinterpret_cast<const short8*>(Qp + (size_t)qrow * DM + lg * 8);
        short8 qf1 = *reinterpret_cast<const short8*>(Qp + (size_t)qrow * DM + 32 + lg * 8);
        f32x4 o[4];
#pragma unroll
        for (int dg = 0; dg < 4; dg++) o[dg] = (f32x4)0.0f;
        float mrun = -INFINITY, lrun = 0.0f;

        const short* kp = Kbh + l * 8;               // +j*4096 +(ks*4+cg)*512
        const short* vp = Vbh + l * 8;
        short8 kc[2][4], vc[2][4];
#pragma unroll
        for (int ks = 0; ks < 2; ks++)
#pragma unroll
            for (int cg = 0; cg < 4; cg++) {
                kc[ks][cg] = *reinterpret_cast<const short8*>(kp + (ks * 4 + cg) * 512);
                vc[ks][cg] = *reinterpret_cast<const short8*>(vp + (ks * 4 + cg) * 512);
            }

        for (int j = 0; j <= jmax; ++j) {
            // ---- swapped QK^T: S^T[key][q] ----
            f32x4 s[4];
#pragma unroll
            for (int cg = 0; cg < 4; cg++) s[cg] = (f32x4)0.0f;
#pragma unroll
            for (int ks = 0; ks < 2; ks++) {
                const short8 qf = ks ? qf1 : qf0;
#pragma unroll
                for (int cg = 0; cg < 4; cg++)
                    s[cg] = __builtin_amdgcn_mfma_f32_16x16x32_bf16(kc[ks][cg], qf, s[cg], 0, 0, 0);
            }
            if (j < jmax) {   // prefetch next K tile (coalesced 1KB loads); hides under softmax+PV
                kp += 4096;
#pragma unroll
                for (int ks = 0; ks < 2; ks++)
#pragma unroll
                    for (int cg = 0; cg < 4; cg++)
                        kc[ks][cg] = *reinterpret_cast<const short8*>(kp + (ks * 4 + cg) * 512);
            }
            if (j == jmax) {  // causal mask: s[cg][r] is logical key (cg>>1)*32+lg*8+(cg&1)*4+r
#pragma unroll
                for (int cg = 0; cg < 4; cg++)
#pragma unroll
                    for (int r = 0; r < 4; r++) {
                        int n = ((cg >> 1) << 5) + (lg << 3) + ((cg & 1) << 2) + r;
                        if (j * 64 + n > qrow) s[cg][r] = -INFINITY;
                    }
            }
            // ---- in-register online softmax (exp2 domain) ----
            float mx0 = fmaxf(fmaxf(s[0][0], s[0][1]), fmaxf(s[0][2], s[0][3]));
            float mx1 = fmaxf(fmaxf(s[1][0], s[1][1]), fmaxf(s[1][2], s[1][3]));
            float mx2 = fmaxf(fmaxf(s[2][0], s[2][1]), fmaxf(s[2][2], s[2][3]));
            float mx3 = fmaxf(fmaxf(s[3][0], s[3][1]), fmaxf(s[3][2], s[3][3]));
            float vmax = fmaxf(fmaxf(mx0, mx1), fmaxf(mx2, mx3));
            vmax = fmaxf(vmax, __shfl_xor(vmax, 16));
            vmax = fmaxf(vmax, __shfl_xor(vmax, 32));
            if (!__all(vmax - mrun <= 8.0f)) {   // defer-max (T13)
                float mn = fmaxf(mrun, vmax);
                float scl = exp2f(mrun - mn);
                mrun = mn; lrun *= scl;
#pragma unroll
                for (int dg = 0; dg < 4; dg++)
#pragma unroll
                    for (int r = 0; r < 4; r++) o[dg][r] *= scl;
            }
            float rs = 0.0f;
#pragma unroll
            for (int cg = 0; cg < 4; cg++)
#pragma unroll
                for (int r = 0; r < 4; r++) {
                    float p = exp2f(s[cg][r] - mrun);
                    s[cg][r] = p;
                    rs += p;
                }
            rs += __shfl_xor(rs, 16);
            rs += __shfl_xor(rs, 32);
            lrun += rs;
            // ---- P already in B-fragment order: in-lane pack ----
            short8 pf0, pf1;
#pragma unroll
            for (int r = 0; r < 4; r++) {
                pf0[r] = f2b(s[0][r]); pf0[4 + r] = f2b(s[1][r]);
                pf1[r] = f2b(s[2][r]); pf1[4 + r] = f2b(s[3][r]);
            }
            // ---- PV: O^T[d][q] = mfma(V^T_frag, P_frag) ----
#pragma unroll
            for (int ks = 0; ks < 2; ks++) {
                const short8 pf = ks ? pf1 : pf0;
#pragma unroll
                for (int dg = 0; dg < 4; dg++)
                    o[dg] = __builtin_amdgcn_mfma_f32_16x16x32_bf16(vc[ks][dg], pf, o[dg], 0, 0, 0);
            }
            if (j < jmax) {   // prefetch next V tile; hides under next QK^T+softmax
                vp += 4096;
#pragma unroll
                for (int ks = 0; ks < 2; ks++)
#pragma unroll
                    for (int cg = 0; cg < 4; cg++)
                        vc[ks][cg] = *reinterpret_cast<const short8*>(vp + (ks * 4 + cg) * 512);
            }
        }
        // ---- write O^T: lane holds d = dg*16+lg*4+r for its q-row ----
        float rinv = 1.0f / lrun;
#pragma unroll
        for (int dg = 0; dg < 4; dg++) {
            short4v ov;
#pragma unroll
            for (int r = 0; r < 4; r++) ov[r] = f2b(o[dg][r] * rinv);
            *reinterpret_cast<short4v*>(Ap + (size_t)qrow * DM + dg * 16 + lg * 4) = ov;
        }
    }
}

extern "C" void kernel_launch(void* const* d_in, const int* in_sizes, int n_in,
                              void* d_out, int out_size, void* d_ws, size_t ws_size,
                              hipStream_t stream) {
    const float* x  = (const float*)d_in[0];
    const float* Wq = (const float*)d_in[1];
    const float* bq = (const float*)d_in[2];
    const float* Wk = (const float*)d_in[3];
    const float* bk = (const float*)d_in[4];
    const float* Wv = (const float*)d_in[5];
    const float* bv = (const float*)d_in[6];
    const float* Wo = (const float*)d_in[7];
    const float* bo = (const float*)d_in[8];

    float* out = (float*)d_out;
    float* presentK = out + (size_t)4194304;
    float* presentV = presentK + (size_t)4194304;

    char* ws = (char*)d_ws;
    short* xb    = (short*)(ws);
    short* Wqt   = (short*)(ws + ((size_t)8  << 20));
    short* Wkt   = (short*)(ws + ((size_t)10 << 20));
    short* Wvt   = (short*)(ws + ((size_t)12 << 20));
    short* Wot   = (short*)(ws + ((size_t)14 << 20));
    short* Qb    = (short*)(ws + ((size_t)16 << 20));
    short* Kfrag = (short*)(ws + ((size_t)24 << 20));   // [bh][j][ks][cg][lane][8] bf16, 8MB
    short* Vfrag = (short*)(ws + ((size_t)32 << 20));   // [bh][j][ks][dg][lane][8] bf16, 8MB
    short* Ab    = (short*)(ws + ((size_t)40 << 20));

    k_convert_x<<<dim3(4096), dim3(256), 0, stream>>>(x, xb);
    k_transpose_w4<<<dim3(32, 32, 4), dim3(32, 8), 0, stream>>>(
        Wq, Wk, Wv, Wo, Wqt, Wkt, Wvt, Wot);
    k_gemm_qkv<<<dim3(8, 32, 3), dim3(256), 0, stream>>>(
        xb, Wqt, Wkt, Wvt, bq, bk, bv, Qb, Kfrag, Vfrag, presentK, presentV);
    k_attn<<<dim3(2048), dim3(64), 0, stream>>>(Qb, Kfrag, Vfrag, Ab);
    k_gemm_o<<<dim3(8, 32), dim3(256), 0, stream>>>(Ab, Wot, bo, out);
}